// Round 1
// baseline (30.697 us; speedup 1.0000x reference)
//
#include <hip/hip_runtime.h>

#define EMB_D 64

// One 64-lane wave per output row; lane index == embedding dim.
// Computes s = sum_l emb[idx[l]][d], sq = sum_l emb^2, then
// scalar = sum_d 0.5*(s^2 - sq)*h1[d] + sum_l w[idx[l]] via wave reduce.
template<int L>
__global__ void fm_pool_kernel(const float* __restrict__ emb,
                               const float* __restrict__ w,
                               const int* __restrict__ idx,
                               const float* __restrict__ h1,
                               const float* __restrict__ gbias,
                               int add_bias,
                               int N,
                               float* __restrict__ out,
                               int scalar_col, int one_col) {
  int gtid = blockIdx.x * blockDim.x + threadIdx.x;
  int row  = gtid >> 6;
  int lane = threadIdx.x & 63;
  if (row >= N) return;

  const int* ridx = idx + (size_t)row * L;

  float s = 0.f, sq = 0.f;
#pragma unroll
  for (int l = 0; l < L; ++l) {
    int id  = ridx[l];                       // wave-uniform load
    float e = emb[(size_t)id * EMB_D + lane]; // 256B coalesced per row
    s  += e;
    sq += e * e;
  }

  float wsum = 0.f;
#pragma unroll
  for (int l = lane; l < L; l += 64) wsum += w[ridx[l]];

  float part = 0.5f * (s * s - sq) * h1[lane] + wsum;
#pragma unroll
  for (int off = 32; off >= 1; off >>= 1)
    part += __shfl_down(part, off, 64);

  float* orow = out + (size_t)row * (EMB_D + 2);
  orow[lane] = s;
  if (lane == 0) {
    orow[scalar_col] = part + (add_bias ? gbias[0] : 0.f);
    orow[one_col]    = 1.0f;
  }
}

__global__ void copy_h2_kernel(const float* __restrict__ h2, float* __restrict__ out) {
  out[threadIdx.x] = h2[threadIdx.x];
}

extern "C" void kernel_launch(void* const* d_in, const int* in_sizes, int n_in,
                              void* d_out, int out_size, void* d_ws, size_t ws_size,
                              hipStream_t stream) {
  const float* uemb = (const float*)d_in[0];
  const float* iemb = (const float*)d_in[1];
  const float* uw   = (const float*)d_in[2];
  const float* iw   = (const float*)d_in[3];
  const float* gb   = (const float*)d_in[4];
  const float* h1   = (const float*)d_in[5];
  const float* h2   = (const float*)d_in[6];
  const int*   uidx = (const int*)d_in[7];
  const int*   iidx = (const int*)d_in[8];

  const int NU = 4096, NI = 16384;
  const int LD = EMB_D + 2; // 66

  float* P  = (float*)d_out;
  float* Q  = P + (size_t)NU * LD;
  float* H2 = Q + (size_t)NI * LD;

  dim3 blk(256); // 4 waves/block, 1 row per wave

  // Users: scalar (bi.h1 + sum w + bias) at col 64, ones at col 65
  fm_pool_kernel<50><<<dim3((NU * 64 + 255) / 256), blk, 0, stream>>>(
      uemb, uw, uidx, h1, gb, /*add_bias=*/1, NU, P, /*scalar_col=*/64, /*one_col=*/65);

  // Items: ones at col 64, scalar at col 65, no bias
  fm_pool_kernel<20><<<dim3((NI * 64 + 255) / 256), blk, 0, stream>>>(
      iemb, iw, iidx, h1, gb, /*add_bias=*/0, NI, Q, /*scalar_col=*/65, /*one_col=*/64);

  // h2 passthrough
  copy_h2_kernel<<<1, 64, 0, stream>>>(h2, H2);
}

// Round 2
// 27.218 us; speedup vs baseline: 1.1278x; 1.1278x over previous
//
#include <hip/hip_runtime.h>

#define EMB_D 64
#define NU 4096
#define NI 16384
#define LDOUT (EMB_D + 2)  // 66

__device__ __forceinline__ float4 ld4(const float* p) {
  return *reinterpret_cast<const float4*>(p);
}

// One 64-lane wave per output row.
// lane = g*16 + sub : g = which of 4 consecutive features, sub = dim quad.
template<int L>
__device__ __forceinline__ void fm_row(const float* __restrict__ emb,
                                       const float* __restrict__ w,
                                       const int* __restrict__ idx, int row,
                                       const float* __restrict__ h1,
                                       float bias, float* __restrict__ out,
                                       int scalar_col, int one_col, int lane) {
  const int* ridx = idx + (size_t)row * L;
  const int g = lane >> 4;
  const int sub = lane & 15;

  float4 s  = make_float4(0.f, 0.f, 0.f, 0.f);
  float4 sq = make_float4(0.f, 0.f, 0.f, 0.f);

  constexpr int LM = L & ~3;
#pragma unroll
  for (int l = 0; l < LM; l += 4) {
    int id = ridx[l + g];
    float4 e = ld4(emb + (size_t)id * EMB_D + sub * 4);
    s.x += e.x; s.y += e.y; s.z += e.z; s.w += e.w;
    sq.x += e.x * e.x; sq.y += e.y * e.y; sq.z += e.z * e.z; sq.w += e.w * e.w;
  }
  if constexpr (LM != L) {
    if (g < (L - LM)) {
      int id = ridx[LM + g];
      float4 e = ld4(emb + (size_t)id * EMB_D + sub * 4);
      s.x += e.x; s.y += e.y; s.z += e.z; s.w += e.w;
      sq.x += e.x * e.x; sq.y += e.y * e.y; sq.z += e.z * e.z; sq.w += e.w * e.w;
    }
  }

  // merge the 4 feature-groups: lanes xor 16, 32
#pragma unroll
  for (int off = 16; off <= 32; off <<= 1) {
    s.x += __shfl_xor(s.x, off, 64);  s.y += __shfl_xor(s.y, off, 64);
    s.z += __shfl_xor(s.z, off, 64);  s.w += __shfl_xor(s.w, off, 64);
    sq.x += __shfl_xor(sq.x, off, 64); sq.y += __shfl_xor(sq.y, off, 64);
    sq.z += __shfl_xor(sq.z, off, 64); sq.w += __shfl_xor(sq.w, off, 64);
  }

  // bi . h1 : only group 0 contributes (s/sq replicated across groups)
  float part = 0.f;
  if (g == 0) {
    float4 h = ld4(h1 + sub * 4);
    part = 0.5f * ((s.x * s.x - sq.x) * h.x + (s.y * s.y - sq.y) * h.y +
                   (s.z * s.z - sq.z) * h.z + (s.w * s.w - sq.w) * h.w);
  }
  // w-gather sum: one feature per lane (L <= 64)
  if (lane < L) part += w[ridx[lane]];

#pragma unroll
  for (int off = 32; off >= 1; off >>= 1) part += __shfl_down(part, off, 64);

  float* orow = out + (size_t)row * LDOUT;
  if (g == 0) {
    // row stride 264 B -> only 8B-aligned; use float2 stores
    *reinterpret_cast<float2*>(orow + sub * 4)     = make_float2(s.x, s.y);
    *reinterpret_cast<float2*>(orow + sub * 4 + 2) = make_float2(s.z, s.w);
  }
  if (lane == 0) {
    orow[scalar_col] = part + bias;
    orow[one_col]    = 1.0f;
  }
}

__global__ __launch_bounds__(256) void fm_fused(
    const float* __restrict__ uemb, const float* __restrict__ iemb,
    const float* __restrict__ uw, const float* __restrict__ iw,
    const float* __restrict__ gb, const float* __restrict__ h1,
    const float* __restrict__ h2, const int* __restrict__ uidx,
    const int* __restrict__ iidx, float* __restrict__ out) {
  int wid  = blockIdx.x * 4 + (threadIdx.x >> 6);
  int lane = threadIdx.x & 63;

  float* P  = out;
  float* Q  = P + (size_t)NU * LDOUT;
  float* H2 = Q + (size_t)NI * LDOUT;

  if (wid < NU) {
    fm_row<50>(uemb, uw, uidx, wid, h1, gb[0], P, /*scalar_col=*/64, /*one_col=*/65, lane);
  } else if (wid < NU + NI) {
    fm_row<20>(iemb, iw, iidx, wid - NU, h1, 0.f, Q, /*scalar_col=*/65, /*one_col=*/64, lane);
  } else if (wid == NU + NI) {
    H2[lane] = h2[lane];
  }
}

extern "C" void kernel_launch(void* const* d_in, const int* in_sizes, int n_in,
                              void* d_out, int out_size, void* d_ws, size_t ws_size,
                              hipStream_t stream) {
  const float* uemb = (const float*)d_in[0];
  const float* iemb = (const float*)d_in[1];
  const float* uw   = (const float*)d_in[2];
  const float* iw   = (const float*)d_in[3];
  const float* gb   = (const float*)d_in[4];
  const float* h1   = (const float*)d_in[5];
  const float* h2   = (const float*)d_in[6];
  const int*   uidx = (const int*)d_in[7];
  const int*   iidx = (const int*)d_in[8];

  // (NU + NI) row-waves + 1 wave for h2, 4 waves per 256-thread block
  int nwaves = NU + NI + 1;
  int nblocks = (nwaves + 3) / 4;  // 5121

  fm_fused<<<dim3(nblocks), dim3(256), 0, stream>>>(
      uemb, iemb, uw, iw, gb, h1, h2, uidx, iidx, (float*)d_out);
}

// Round 4
// 25.575 us; speedup vs baseline: 1.2003x; 1.0642x over previous
//
#include <hip/hip_runtime.h>

#define EMB_D 64
#define NU 4096
#define NI 16384
#define LDOUT (EMB_D + 2)  // 66

__device__ __forceinline__ float4 ld4(const float* p) {
  return *reinterpret_cast<const float4*>(p);
}

// One 64-lane wave per output row.
// lane = g*16 + sub : g = which of 4 consecutive features, sub = dim quad.
// idx row is loaded ONCE (lane i holds idx[i]); per-gather indices come from
// ds_bpermute broadcast. Addresses are 32-bit byte offsets from scalar base.
// RULE: every __shfl executes with ALL 64 lanes active (no cross-lane op
// inside a divergent branch) — inactive source lanes return garbage.
template<int L>
__device__ __forceinline__ void fm_row(const float* __restrict__ emb,
                                       const float* __restrict__ w,
                                       const int* __restrict__ idx, int row,
                                       const float* __restrict__ h1,
                                       float bias, float* __restrict__ out,
                                       int scalar_col, int one_col, int lane) {
  const int* ridx = idx + (size_t)row * L;
  const int g = lane >> 4;
  const int sub = lane & 15;

  // one coalesced idx load for the whole row (L <= 64)
  int myidx = (lane < L) ? ridx[lane] : 0;

  const char* base = (const char*)emb;

  float4 s  = make_float4(0.f, 0.f, 0.f, 0.f);
  float4 sq = make_float4(0.f, 0.f, 0.f, 0.f);

  constexpr int LM = L & ~3;
#pragma unroll
  for (int l = 0; l < LM; l += 4) {
    int id = __shfl(myidx, l + g, 64);          // all lanes active
    unsigned boff = ((unsigned)id << 8) | (unsigned)(sub << 4);
    float4 e = ld4((const float*)(base + boff)); // 1 KiB per wave instr
    s.x += e.x; s.y += e.y; s.z += e.z; s.w += e.w;
    sq.x += e.x * e.x; sq.y += e.y * e.y; sq.z += e.z * e.z; sq.w += e.w * e.w;
  }
  if constexpr (LM != L) {
    constexpr int TAIL = L - LM;
    // shfl OUTSIDE the divergent region: clamp src lane for non-participants
    int srcl = LM + (g < TAIL ? g : 0);
    int id = __shfl(myidx, srcl, 64);           // all lanes active
    if (g < TAIL) {
      unsigned boff = ((unsigned)id << 8) | (unsigned)(sub << 4);
      float4 e = ld4((const float*)(base + boff));
      s.x += e.x; s.y += e.y; s.z += e.z; s.w += e.w;
      sq.x += e.x * e.x; sq.y += e.y * e.y; sq.z += e.z * e.z; sq.w += e.w * e.w;
    }
  }

  // merge ONLY s across the 4 feature-groups (sq handled as scalar partials)
#pragma unroll
  for (int off = 16; off <= 32; off <<= 1) {
    s.x += __shfl_xor(s.x, off, 64);  s.y += __shfl_xor(s.y, off, 64);
    s.z += __shfl_xor(s.z, off, 64);  s.w += __shfl_xor(s.w, off, 64);
  }

  // scalar = 0.5*sum_d(s_d^2 h_d) - 0.5*sum_d(sq_d h_d) + sum_l w[idx_l]
  // term A: group-0 lanes cover all 64 dims with merged s.
  // term B: every lane's local sq partial; summing over all 64 lanes gives
  //         the full sum over groups AND dims.
  float4 h = ld4(h1 + sub * 4);
  float part = -0.5f * (sq.x * h.x + sq.y * h.y + sq.z * h.z + sq.w * h.w);
  if (g == 0)
    part += 0.5f * (s.x * s.x * h.x + s.y * s.y * h.y +
                    s.z * s.z * h.z + s.w * s.w * h.w);
  if (lane < L) part += w[myidx];

#pragma unroll
  for (int off = 32; off >= 1; off >>= 1) part += __shfl_down(part, off, 64);

  float* orow = out + (size_t)row * LDOUT;
  if (g == 0) {
    // row stride 264 B -> only 8B-aligned; use float2 stores
    *reinterpret_cast<float2*>(orow + sub * 4)     = make_float2(s.x, s.y);
    *reinterpret_cast<float2*>(orow + sub * 4 + 2) = make_float2(s.z, s.w);
  }
  if (lane == 0) {
    orow[scalar_col] = part + bias;
    orow[one_col]    = 1.0f;
  }
}

__global__ __launch_bounds__(256) void fm_fused(
    const float* __restrict__ uemb, const float* __restrict__ iemb,
    const float* __restrict__ uw, const float* __restrict__ iw,
    const float* __restrict__ gb, const float* __restrict__ h1,
    const float* __restrict__ h2, const int* __restrict__ uidx,
    const int* __restrict__ iidx, float* __restrict__ out) {
  int wid  = blockIdx.x * 4 + (threadIdx.x >> 6);
  int lane = threadIdx.x & 63;

  float* P  = out;
  float* Q  = P + (size_t)NU * LDOUT;
  float* H2 = Q + (size_t)NI * LDOUT;

  if (wid < NU) {
    fm_row<50>(uemb, uw, uidx, wid, h1, gb[0], P, /*scalar_col=*/64, /*one_col=*/65, lane);
  } else if (wid < NU + NI) {
    fm_row<20>(iemb, iw, iidx, wid - NU, h1, 0.f, Q, /*scalar_col=*/65, /*one_col=*/64, lane);
  } else if (wid == NU + NI) {
    H2[lane] = h2[lane];
  }
}

extern "C" void kernel_launch(void* const* d_in, const int* in_sizes, int n_in,
                              void* d_out, int out_size, void* d_ws, size_t ws_size,
                              hipStream_t stream) {
  const float* uemb = (const float*)d_in[0];
  const float* iemb = (const float*)d_in[1];
  const float* uw   = (const float*)d_in[2];
  const float* iw   = (const float*)d_in[3];
  const float* gb   = (const float*)d_in[4];
  const float* h1   = (const float*)d_in[5];
  const float* h2   = (const float*)d_in[6];
  const int*   uidx = (const int*)d_in[7];
  const int*   iidx = (const int*)d_in[8];

  int nwaves = NU + NI + 1;
  int nblocks = (nwaves + 3) / 4;  // 5121

  fm_fused<<<dim3(nblocks), dim3(256), 0, stream>>>(
      uemb, iemb, uw, iw, gb, h1, h2, uidx, iidx, (float*)d_out);
}

// Round 5
// 25.462 us; speedup vs baseline: 1.2056x; 1.0044x over previous
//
#include <hip/hip_runtime.h>

#define EMB_D 64
#define NU 4096
#define NI 16384
#define LDOUT (EMB_D + 2)  // 66

__device__ __forceinline__ float4 ld4(const float* p) {
  return *reinterpret_cast<const float4*>(p);
}

// ---------------- user path: one 64-lane wave per row (L=50) ----------------
// lane = g*16 + sub : g = which of 4 consecutive features, sub = dim quad.
// RULE: every __shfl executes with ALL 64 lanes active.
__device__ __forceinline__ void fm_user_row(const float* __restrict__ emb,
                                            const float* __restrict__ w,
                                            const int* __restrict__ idx, int row,
                                            const float* __restrict__ h1,
                                            float bias, float* __restrict__ out,
                                            int lane) {
  constexpr int L = 50;
  const int* ridx = idx + (size_t)row * L;
  const int g = lane >> 4;
  const int sub = lane & 15;

  int myidx = (lane < L) ? ridx[lane] : 0;
  const char* base = (const char*)emb;

  float4 s  = make_float4(0.f, 0.f, 0.f, 0.f);
  float4 sq = make_float4(0.f, 0.f, 0.f, 0.f);

  constexpr int LM = L & ~3;  // 48
#pragma unroll
  for (int l = 0; l < LM; l += 4) {
    int id = __shfl(myidx, l + g, 64);
    unsigned boff = ((unsigned)id << 8) | (unsigned)(sub << 4);
    float4 e = ld4((const float*)(base + boff));
    s.x += e.x; s.y += e.y; s.z += e.z; s.w += e.w;
    sq.x += e.x * e.x; sq.y += e.y * e.y; sq.z += e.z * e.z; sq.w += e.w * e.w;
  }
  {
    constexpr int TAIL = L - LM;  // 2
    int srcl = LM + (g < TAIL ? g : 0);
    int id = __shfl(myidx, srcl, 64);  // all lanes active
    if (g < TAIL) {
      unsigned boff = ((unsigned)id << 8) | (unsigned)(sub << 4);
      float4 e = ld4((const float*)(base + boff));
      s.x += e.x; s.y += e.y; s.z += e.z; s.w += e.w;
      sq.x += e.x * e.x; sq.y += e.y * e.y; sq.z += e.z * e.z; sq.w += e.w * e.w;
    }
  }

#pragma unroll
  for (int off = 16; off <= 32; off <<= 1) {
    s.x += __shfl_xor(s.x, off, 64);  s.y += __shfl_xor(s.y, off, 64);
    s.z += __shfl_xor(s.z, off, 64);  s.w += __shfl_xor(s.w, off, 64);
  }

  float4 h = ld4(h1 + sub * 4);
  float part = -0.5f * (sq.x * h.x + sq.y * h.y + sq.z * h.z + sq.w * h.w);
  if (g == 0)
    part += 0.5f * (s.x * s.x * h.x + s.y * s.y * h.y +
                    s.z * s.z * h.z + s.w * s.w * h.w);
  if (lane < L) part += w[myidx];

#pragma unroll
  for (int off = 32; off >= 1; off >>= 1) part += __shfl_down(part, off, 64);

  float* orow = out + (size_t)row * LDOUT;
  if (g == 0) {
    *reinterpret_cast<float2*>(orow + sub * 4)     = make_float2(s.x, s.y);
    *reinterpret_cast<float2*>(orow + sub * 4 + 2) = make_float2(s.z, s.w);
  }
  if (lane == 0) {
    orow[64] = part + bias;  // scalar col
    orow[65] = 1.0f;         // ones col
  }
}

// ------------- item path: TWO rows per 64-lane wave (L=20 each) -------------
// r = lane>>5 (row within pair), lr = lane&31, g2 = (lr>>4), sub = lane&15.
// idx: row r's 20 features live in lanes r*32 + 0..19.
// 10 gather iters, 2 features x 2 rows per instr -> 10 independent loads.
__device__ __forceinline__ void fm_item_pair(const float* __restrict__ emb,
                                             const float* __restrict__ w,
                                             const int* __restrict__ idx, int pair,
                                             const float* __restrict__ h1,
                                             float* __restrict__ out, int lane) {
  constexpr int L = 20;
  const int r  = lane >> 5;
  const int lr = lane & 31;
  const int g2 = lr >> 4;
  const int sub = lane & 15;
  const int row = pair * 2 + r;

  // coalesced: two 80B segments
  int myidx = (lr < L) ? idx[(size_t)row * L + lr] : 0;
  const char* base = (const char*)emb;

  float4 s  = make_float4(0.f, 0.f, 0.f, 0.f);
  float4 sq = make_float4(0.f, 0.f, 0.f, 0.f);

#pragma unroll
  for (int k = 0; k < L / 2; ++k) {
    int src = (r << 5) + 2 * k + g2;           // feature 2k+g2 of row r
    int id = __shfl(myidx, src, 64);           // all lanes active
    unsigned boff = ((unsigned)id << 8) | (unsigned)(sub << 4);
    float4 e = ld4((const float*)(base + boff));
    s.x += e.x; s.y += e.y; s.z += e.z; s.w += e.w;
    sq.x += e.x * e.x; sq.y += e.y * e.y; sq.z += e.z * e.z; sq.w += e.w * e.w;
  }

  // merge the 2 feature-groups within each 32-lane row half (xor 16)
  s.x += __shfl_xor(s.x, 16, 64);  s.y += __shfl_xor(s.y, 16, 64);
  s.z += __shfl_xor(s.z, 16, 64);  s.w += __shfl_xor(s.w, 16, 64);

  float4 h = ld4(h1 + sub * 4);
  float part = -0.5f * (sq.x * h.x + sq.y * h.y + sq.z * h.z + sq.w * h.w);
  if (g2 == 0)
    part += 0.5f * (s.x * s.x * h.x + s.y * s.y * h.y +
                    s.z * s.z * h.z + s.w * s.w * h.w);
  if (lr < L) part += w[myidx];

  // 32-lane reduce per row half: xor offsets <=16 never cross bit 5
#pragma unroll
  for (int off = 16; off >= 1; off >>= 1) part += __shfl_xor(part, off, 64);

  float* orow = out + (size_t)row * LDOUT;
  if (g2 == 0) {
    *reinterpret_cast<float2*>(orow + sub * 4)     = make_float2(s.x, s.y);
    *reinterpret_cast<float2*>(orow + sub * 4 + 2) = make_float2(s.z, s.w);
  }
  if (lr == 0) {
    orow[64] = 1.0f;   // ones col
    orow[65] = part;   // scalar col (no bias for items)
  }
}

__global__ __launch_bounds__(256) void fm_fused(
    const float* __restrict__ uemb, const float* __restrict__ iemb,
    const float* __restrict__ uw, const float* __restrict__ iw,
    const float* __restrict__ gb, const float* __restrict__ h1,
    const float* __restrict__ h2, const int* __restrict__ uidx,
    const int* __restrict__ iidx, float* __restrict__ out) {
  int wid  = blockIdx.x * 4 + (threadIdx.x >> 6);
  int lane = threadIdx.x & 63;

  float* P  = out;
  float* Q  = P + (size_t)NU * LDOUT;
  float* H2 = Q + (size_t)NI * LDOUT;

  if (wid < NU) {
    fm_user_row(uemb, uw, uidx, wid, h1, gb[0], P, lane);
  } else if (wid < NU + NI / 2) {
    fm_item_pair(iemb, iw, iidx, wid - NU, h1, Q, lane);
  } else if (wid == NU + NI / 2) {
    H2[lane] = h2[lane];
  }
}

extern "C" void kernel_launch(void* const* d_in, const int* in_sizes, int n_in,
                              void* d_out, int out_size, void* d_ws, size_t ws_size,
                              hipStream_t stream) {
  const float* uemb = (const float*)d_in[0];
  const float* iemb = (const float*)d_in[1];
  const float* uw   = (const float*)d_in[2];
  const float* iw   = (const float*)d_in[3];
  const float* gb   = (const float*)d_in[4];
  const float* h1   = (const float*)d_in[5];
  const float* h2   = (const float*)d_in[6];
  const int*   uidx = (const int*)d_in[7];
  const int*   iidx = (const int*)d_in[8];

  int nwaves = NU + NI / 2 + 1;       // 12289
  int nblocks = (nwaves + 3) / 4;     // 3073

  fm_fused<<<dim3(nblocks), dim3(256), 0, stream>>>(
      uemb, iemb, uw, iw, gb, h1, h2, uidx, iidx, (float*)d_out);
}